// Round 4
// baseline (848.512 us; speedup 1.0000x reference)
//
#include <hip/hip_runtime.h>
#include <math.h>

#define NB 8
#define NT 800
#define NC 8
#define NF 513
#define NFT 9      // ceil(513/64) f-tiles of 64 lanes
#define NTC 20     // t chunks (blocks along t)
#define TCHUNK 40  // t per block
#define TS 4       // t per staged tile
#define NSTG (TCHUNK / TS)
#define NE 146     // 72 (psd_s tri) + 72 (psd_n tri) + S_s + S_n
#define NPAIR 36
#define STRIDE_BUF (72 * 64)   // floats per stage buffer: 64 x-rows + 8 mask-rows

// Compact layout: comp[((b*NFT+ft)*NE + entry)*64 + fl]
// entry 2p/2p+1    : psd_s pair p (c<=e), re/im, p = c*8 - c(c+1)/2 + e
// entry 72+2p/...+1: psd_n pair p
// entry 144/145    : S_s / S_n (accumulated over t-chunk blocks)

// Diagonal-grouped pair split: wave w owns 9 of the 36 (c<=e) pairs.
// d0(8)+d7(1) / d1(7)+d6(2) / d2(6)+d5(3) / d3(5)+d4(4)
constexpr int PCt[4][9] = {
    {0, 1, 2, 3, 4, 5, 6, 7, 0},
    {0, 1, 2, 3, 4, 5, 6, 0, 1},
    {0, 1, 2, 3, 4, 5, 0, 1, 2},
    {0, 1, 2, 3, 4, 0, 1, 2, 3}};
constexpr int PEt[4][9] = {
    {0, 1, 2, 3, 4, 5, 6, 7, 7},
    {1, 2, 3, 4, 5, 6, 7, 6, 7},
    {2, 3, 4, 5, 6, 7, 5, 6, 7},
    {3, 4, 5, 6, 7, 4, 5, 6, 7}};

// ---------------------------------------------------------------------------
// Mask reduce over c + transpose -> mred[b][t][f], float4 loads along t.
__global__ __launch_bounds__(256)
void k_maskred(const float* __restrict__ ms, const float* __restrict__ mn,
               float* __restrict__ mrs, float* __restrict__ mrn) {
  __shared__ float ts[64][65];   // 65 pad: both phases <=2-way bank aliasing (free)
  __shared__ float tn[64][65];
  const int ft = blockIdx.x, tt = blockIdx.y, b = blockIdx.z;
  const int f0 = ft * 64, t0 = tt * 64;
  const int tq = threadIdx.x & 15;   // t-quad: 16 quads = 64 t
  const int fy = threadIdx.x >> 4;   // 0..15
  const int t = t0 + tq * 4;
  const bool tvalid = (t < NT);      // NT%4==0 so t<NT implies whole quad valid

#pragma unroll
  for (int p = 0; p < 4; p++) {
    const int fl = p * 16 + fy;
    const int f = f0 + fl;
    float4 as = make_float4(0.f, 0.f, 0.f, 0.f);
    float4 an = make_float4(0.f, 0.f, 0.f, 0.f);
    if (f < NF && tvalid) {
      const float* mbs = ms + (((size_t)b * NF + f) * NC) * NT + t;
      const float* mbn = mn + (((size_t)b * NF + f) * NC) * NT + t;
#pragma unroll
      for (int c = 0; c < NC; c++) {
        const float4 a = *(const float4*)(mbs + c * NT);
        as.x += fmaxf(a.x, 1e-6f); as.y += fmaxf(a.y, 1e-6f);
        as.z += fmaxf(a.z, 1e-6f); as.w += fmaxf(a.w, 1e-6f);
        const float4 q = *(const float4*)(mbn + c * NT);
        an.x += fmaxf(q.x, 1e-6f); an.y += fmaxf(q.y, 1e-6f);
        an.z += fmaxf(q.z, 1e-6f); an.w += fmaxf(q.w, 1e-6f);
      }
    }
    ts[fl][tq * 4 + 0] = as.x * 0.125f; ts[fl][tq * 4 + 1] = as.y * 0.125f;
    ts[fl][tq * 4 + 2] = as.z * 0.125f; ts[fl][tq * 4 + 3] = as.w * 0.125f;
    tn[fl][tq * 4 + 0] = an.x * 0.125f; tn[fl][tq * 4 + 1] = an.y * 0.125f;
    tn[fl][tq * 4 + 2] = an.z * 0.125f; tn[fl][tq * 4 + 3] = an.w * 0.125f;
  }
  __syncthreads();
  const int tx = threadIdx.x & 63, wy = threadIdx.x >> 6;
  for (int tl = wy; tl < 64; tl += 4) {
    const int tg = t0 + tl, f = f0 + tx;
    if (tg < NT && f < NF) {
      mrs[((size_t)b * NT + tg) * NF + f] = ts[tx][tl];
      mrn[((size_t)b * NT + tg) * NF + f] = tn[tx][tl];
    }
  }
}

// ---------------------------------------------------------------------------
// Stage TS t-steps of x (re,im; 8 c) + both masks into LDS via async
// global_load_lds (width 4: 64 lanes x 4B = one 256B row per instruction).
// Row layout: row = t*16 + c*2 + ri (rows 0..63), masks at 64 + t*2 + {s,n}.
// LDS dest is wave-uniform base + lane*4 (linear, guide §5); global source is
// per-lane (fglob clamped for the ft=8 tail — garbage lands in unused slots).
__device__ __forceinline__ void stage_tile(const float* __restrict__ drb,
                                           const float* __restrict__ dib,
                                           const float* __restrict__ mrsb,
                                           const float* __restrict__ mrnb,
                                           float* buf, int tbase, int w, int fglob) {
#pragma unroll
  for (int r = 0; r < 18; ++r) {
    const int row = r * 4 + w;          // wave-uniform
    const float* src;
    if (r < 16) {                        // x rows (compile-time branch)
      const int t = row >> 4, c = (row >> 1) & 7;
      const float* base = (row & 1) ? dib : drb;
      src = base + ((size_t)(tbase + t) * NC + c) * NF + fglob;
    } else {                             // mask rows
      const int t = (row - 64) >> 1;
      const float* base = (row & 1) ? mrnb : mrsb;
      src = base + (size_t)(tbase + t) * NF + fglob;
    }
    __builtin_amdgcn_global_load_lds(
        (const __attribute__((address_space(1))) void*)src,
        (__attribute__((address_space(3))) void*)(buf + row * 64),
        4, 0, 0);
  }
}

template <int W>
__device__ __forceinline__ void psd_compute_tile(const float* __restrict__ buf,
                                                 int fl,
                                                 float sr[9], float si[9],
                                                 float nr[9], float ni[9],
                                                 float& Ss, float& Sn) {
#pragma unroll
  for (int t = 0; t < TS; ++t) {
    float xr[8], xi[8];
#pragma unroll
    for (int c = 0; c < 8; ++c) {
      xr[c] = buf[(t * 16 + c * 2 + 0) * 64 + fl];
      xi[c] = buf[(t * 16 + c * 2 + 1) * 64 + fl];
    }
    const float ms = buf[(64 + t * 2 + 0) * 64 + fl];
    const float mn = buf[(64 + t * 2 + 1) * 64 + fl];
    if (W == 0) { Ss += ms; Sn += mn; }
#pragma unroll
    for (int k = 0; k < 9; ++k) {
      const int c = PCt[W][k], e = PEt[W][k];   // folds after unroll
      const float pr = xr[c] * xr[e] + xi[c] * xi[e];
      sr[k] += ms * pr; nr[k] += mn * pr;
      if (c != e) {
        const float pi = xi[c] * xr[e] - xr[c] * xi[e];
        si[k] += ms * pi; ni[k] += mn * pi;
      }
    }
  }
}

template <int W>
__device__ __forceinline__ void psd_sweep(float* __restrict__ out,
                                          const float sr[9], const float si[9],
                                          const float nr[9], const float ni[9]) {
#pragma unroll
  for (int k = 0; k < 9; ++k) {
    const int c = PCt[W][k], e = PEt[W][k];
    const int p = c * 8 - (c * (c + 1)) / 2 + e;
    unsafeAtomicAdd(&out[(2 * p) * 64], sr[k]);
    unsafeAtomicAdd(&out[(72 + 2 * p) * 64], nr[k]);
    if (c != e) {
      unsafeAtomicAdd(&out[(2 * p + 1) * 64], si[k]);
      unsafeAtomicAdd(&out[(72 + 2 * p + 1) * 64], ni[k]);
    }
  }
}

// 4 waves per block share one (b,ft,tc) via LDS-staged x (double-buffered,
// async global_load_lds); waves own DISJOINT pair subsets (9 each, 36 acc
// regs/thread) so no cross-wave reduction is needed. (256,4): VGPR cap 128,
// 36.9 KB LDS -> 4 blocks/CU = 16 waves/CU.
__global__ __launch_bounds__(256, 4)
void k_psd(const float* __restrict__ dr, const float* __restrict__ di,
           const float* __restrict__ mrs, const float* __restrict__ mrn,
           float* __restrict__ comp) {
  __shared__ float lds[2 * STRIDE_BUF];   // 36,864 B
  const int tid = threadIdx.x;
  const int fl = tid & 63;
  const int w  = tid >> 6;
  const int ft = blockIdx.x, b = blockIdx.y, tc = blockIdx.z;
  const int fglob = min(ft * 64 + fl, NF - 1);
  const int t0 = tc * TCHUNK;

  const float* drb  = dr  + (size_t)b * NT * NC * NF;
  const float* dib  = di  + (size_t)b * NT * NC * NF;
  const float* mrsb = mrs + (size_t)b * NT * NF;
  const float* mrnb = mrn + (size_t)b * NT * NF;

  float sr[9], si[9], nr[9], ni[9];
#pragma unroll
  for (int k = 0; k < 9; ++k) { sr[k] = 0.f; si[k] = 0.f; nr[k] = 0.f; ni[k] = 0.f; }
  float Ss = 0.f, Sn = 0.f;

  stage_tile(drb, dib, mrsb, mrnb, &lds[0], t0, w, fglob);
  asm volatile("s_waitcnt vmcnt(0)" ::: "memory");
  __syncthreads();

  int cur = 0;
  for (int s = 0; s < NSTG; ++s) {
    if (s + 1 < NSTG)
      stage_tile(drb, dib, mrsb, mrnb, &lds[(cur ^ 1) * STRIDE_BUF],
                 t0 + (s + 1) * TS, w, fglob);
    const float* buf = &lds[cur * STRIDE_BUF];
    switch (w) {   // wave-uniform; no barriers inside arms
      case 0: psd_compute_tile<0>(buf, fl, sr, si, nr, ni, Ss, Sn); break;
      case 1: psd_compute_tile<1>(buf, fl, sr, si, nr, ni, Ss, Sn); break;
      case 2: psd_compute_tile<2>(buf, fl, sr, si, nr, ni, Ss, Sn); break;
      default: psd_compute_tile<3>(buf, fl, sr, si, nr, ni, Ss, Sn); break;
    }
    if (s + 1 < NSTG) {
      asm volatile("s_waitcnt vmcnt(0)" ::: "memory");   // next tile landed
      __syncthreads();
      cur ^= 1;
    }
  }

  // per-wave coalesced atomic sweep of its own 9 pairs (disjoint across waves)
  float* out = comp + ((size_t)(b * NFT + ft) * NE) * 64 + fl;
  switch (w) {
    case 0: psd_sweep<0>(out, sr, si, nr, ni); break;
    case 1: psd_sweep<1>(out, sr, si, nr, ni); break;
    case 2: psd_sweep<2>(out, sr, si, nr, ni); break;
    default: psd_sweep<3>(out, sr, si, nr, ni); break;
  }
  if (w == 0) {
    unsafeAtomicAdd(&out[144 * 64], Ss);
    unsafeAtomicAdd(&out[145 * 64], Sn);
  }
}

// ---------------------------------------------------------------------------
__global__ __launch_bounds__(320)
void k_attention(const float* __restrict__ comp,
                 const float* __restrict__ mlp_w, const float* __restrict__ mlp_b,
                 const float* __restrict__ gvec_w, const float* __restrict__ gvec_b,
                 float* __restrict__ e_buf) {
  __shared__ float feat[NF];
  __shared__ float wred[5];
  const int b = blockIdx.x >> 3, c = blockIdx.x & 7;
  const int tid = threadIdx.x;

  for (int f = tid; f < NF; f += 320) {
    const int ft = f >> 6, fl = f & 63;
    const float* base = comp + (((size_t)b * NFT + ft) * NE) * 64 + fl;
    float rs = 0.f, is = 0.f;
#pragma unroll
    for (int e = 0; e < NC; ++e) {
      if (e == c) continue;
      const int lo = (e < c) ? e : c, hi = (e < c) ? c : e;
      const int p = lo * 8 - (lo * (lo + 1)) / 2 + hi;
      rs += base[(2 * p) * 64];
      const float im = base[(2 * p + 1) * 64];
      is += (e > c) ? im : -im;   // row c: e<c needs conj
    }
    const float S = base[144 * 64];
    feat[f] = sqrtf(rs * rs + is * is) / (7.f * (S + 1e-15f));
  }
  __syncthreads();

  const int a = tid;  // blockDim == 320 == A
  float acc = mlp_b[a];
  for (int f = 0; f < NF; ++f) acc = fmaf(feat[f], mlp_w[f * 320 + a], acc);
  float contrib = tanhf(acc) * gvec_w[a];
#pragma unroll
  for (int off = 32; off > 0; off >>= 1) contrib += __shfl_down(contrib, off);
  if ((tid & 63) == 0) wred[tid >> 6] = contrib;
  __syncthreads();
  if (tid == 0) {
    float s = gvec_b[0];
#pragma unroll
    for (int w = 0; w < 5; ++w) s += wred[w];
    e_buf[blockIdx.x] = s;
  }
}

// ---------------------------------------------------------------------------
// Thread per (b,f,c): duplicated 8x8 complex Cholesky of psd_n per 8-lane
// group, one RHS column solve per thread, softmax(u) in-register,
// trace + u-weighted combine via shfl_xor butterflies over the 8-lane group.
__global__ __launch_bounds__(64)
void k_solve(const float* __restrict__ comp, const float* __restrict__ e_buf,
             float* __restrict__ wsvec) {
  const int lane = threadIdx.x;
  const int c = lane & 7, fsub = lane >> 3;
  const int b = blockIdx.y;
  const int f = blockIdx.x * 8 + fsub;
  if (f >= NF) return;
  const int ft = f >> 6, fl = f & 63;
  const float* base = comp + (((size_t)b * NFT + ft) * NE) * 64 + fl;

  float Ar[8][8], Ai[8][8];
#pragma unroll
  for (int j = 0; j < 8; j++) {
#pragma unroll
    for (int i = j; i < 8; i++) {
      const int p = j * 8 - (j * (j + 1)) / 2 + i;
      Ar[i][j] = base[(72 + 2 * p) * 64];
      Ai[i][j] = (i == j) ? 0.f : -base[(72 + 2 * p + 1) * 64];
    }
  }
#pragma unroll
  for (int i = 0; i < 8; i++) Ar[i][i] += 1e-15f;

  float dinv[8];
#pragma unroll
  for (int k = 0; k < 8; k++) {
    const float d = sqrtf(fmaxf(Ar[k][k], 1e-30f));
    const float id = 1.f / d;
    dinv[k] = id;
#pragma unroll
    for (int i = k + 1; i < 8; i++) { Ar[i][k] *= id; Ai[i][k] *= id; }
#pragma unroll
    for (int j = k + 1; j < 8; j++) {
#pragma unroll
      for (int i = j; i < 8; i++) {
        Ar[i][j] -= Ar[i][k] * Ar[j][k] + Ai[i][k] * Ai[j][k];
        Ai[i][j] -= Ai[i][k] * Ar[j][k] - Ar[i][k] * Ai[j][k];
      }
    }
  }

  // column c of psd_s: s[e] = psd_s[e][c]
  float syr[8], syi[8];
#pragma unroll
  for (int e = 0; e < 8; e++) {
    const int lo = (e < c) ? e : c, hi = (e < c) ? c : e;
    const int p = lo * 8 - (lo * (lo + 1)) / 2 + hi;
    syr[e] = base[(2 * p) * 64];
    const float im = base[(2 * p + 1) * 64];
    syi[e] = (e <= c) ? im : -im;
  }
  float yr[8], yi[8];
#pragma unroll
  for (int i = 0; i < 8; i++) {
    float ar = syr[i], ai = syi[i];
#pragma unroll
    for (int m = 0; m < 8; m++) {
      if (m < i) {
        ar -= Ar[i][m] * yr[m] - Ai[i][m] * yi[m];
        ai -= Ar[i][m] * yi[m] + Ai[i][m] * yr[m];
      }
    }
    yr[i] = ar * dinv[i]; yi[i] = ai * dinv[i];
  }
  float zr[8], zi[8];
#pragma unroll
  for (int i = 7; i >= 0; i--) {
    float ar = yr[i], ai = yi[i];
#pragma unroll
    for (int m = 0; m < 8; m++) {
      if (m > i) {
        ar -= Ar[m][i] * zr[m] + Ai[m][i] * zi[m];
        ai -= Ar[m][i] * zi[m] - Ai[m][i] * zr[m];
      }
    }
    zr[i] = ar * dinv[i]; zi[i] = ai * dinv[i];
  }

  // softmax(2*e) -> u[c]
  float ev[8], mx = -1e30f;
#pragma unroll
  for (int j = 0; j < 8; j++) { ev[j] = 2.f * e_buf[b * 8 + j]; mx = fmaxf(mx, ev[j]); }
  float ssum = 0.f;
#pragma unroll
  for (int j = 0; j < 8; j++) ssum += expf(ev[j] - mx);
  const float uc = expf(ev[c] - mx) / ssum;

  float trr = zr[c], tri = zi[c];
  float wr[8], wi[8];
#pragma unroll
  for (int e = 0; e < 8; e++) { wr[e] = zr[e] * uc; wi[e] = zi[e] * uc; }
#pragma unroll
  for (int m = 1; m <= 4; m <<= 1) {
    trr += __shfl_xor(trr, m); tri += __shfl_xor(tri, m);
#pragma unroll
    for (int e = 0; e < 8; e++) {
      wr[e] += __shfl_xor(wr[e], m);
      wi[e] += __shfl_xor(wi[e], m);
    }
  }

  const float denr = trr + 1e-15f, deni = tri;
  const float inv = 1.f / (denr * denr + deni * deni);
  float2* wv = (float2*)wsvec + ((size_t)b * NF + f) * 8;
  wv[c] = make_float2((wr[c] * denr + wi[c] * deni) * inv,
                      (wi[c] * denr - wr[c] * deni) * inv);
}

// ---------------------------------------------------------------------------
__global__ __launch_bounds__(64)
void k_apply(const float* __restrict__ dr, const float* __restrict__ di,
             const float* __restrict__ wsvec, float* __restrict__ out) {
  const int ft = blockIdx.x, b = blockIdx.y, tt = blockIdx.z;
  const int f = ft * 64 + threadIdx.x;
  if (f >= NF) return;
  float wr[8], wi[8];
  const float2* wv = (const float2*)wsvec + ((size_t)b * NF + f) * 8;
#pragma unroll
  for (int c = 0; c < 8; c++) { float2 w = wv[c]; wr[c] = w.x; wi[c] = w.y; }
  const float* drb = dr + (size_t)b * NT * NC * NF + f;
  const float* dib = di + (size_t)b * NT * NC * NF + f;
  float2* ob = (float2*)out + (size_t)b * NT * NF + f;
  const int t1 = tt * 8 + 8;
  for (int t = tt * 8; t < t1; ++t) {
    float re = 0.f, im = 0.f;
#pragma unroll
    for (int c = 0; c < 8; c++) {
      const float xr = drb[(t * NC + c) * NF];
      const float xi = dib[(t * NC + c) * NF];
      re += wr[c] * xr + wi[c] * xi;   // conj(ws) * x
      im += wr[c] * xi - wi[c] * xr;
    }
    ob[(size_t)t * NF] = make_float2(re, im);
  }
}

extern "C" void kernel_launch(void* const* d_in, const int* in_sizes, int n_in,
                              void* d_out, int out_size, void* d_ws, size_t ws_size,
                              hipStream_t stream) {
  const float* dr     = (const float*)d_in[0];
  const float* di     = (const float*)d_in[1];
  const float* msk_s  = (const float*)d_in[2];
  const float* msk_n  = (const float*)d_in[3];
  const float* mlp_w  = (const float*)d_in[4];
  const float* mlp_b  = (const float*)d_in[5];
  const float* gvec_w = (const float*)d_in[6];
  const float* gvec_b = (const float*)d_in[7];

  float* mrs   = (float*)d_ws;                                   // 3,283,200 floats
  float* mrn   = mrs + (size_t)NB * NT * NF;                     // 3,283,200
  float* comp  = mrn + (size_t)NB * NT * NF;                     // 672,768
  float* e_buf = comp + (size_t)NB * NFT * NE * 64;              // 64
  float* wsvec = e_buf + 64;                                     // 65,664
  float* out   = (float*)d_out;

  hipMemsetAsync(comp, 0, (size_t)NB * NFT * NE * 64 * sizeof(float), stream);
  k_maskred<<<dim3(NFT, 13, NB), 256, 0, stream>>>(msk_s, msk_n, mrs, mrn);
  k_psd<<<dim3(NFT, NB, NTC), 256, 0, stream>>>(dr, di, mrs, mrn, comp);
  k_attention<<<64, 320, 0, stream>>>(comp, mlp_w, mlp_b, gvec_w, gvec_b, e_buf);
  k_solve<<<dim3(65, NB), 64, 0, stream>>>(comp, e_buf, wsvec);
  k_apply<<<dim3(NFT, NB, 100), 64, 0, stream>>>(dr, di, wsvec, out);
}

// Round 5
// 512.502 us; speedup vs baseline: 1.6556x; 1.6556x over previous
//
#include <hip/hip_runtime.h>
#include <math.h>

#define NB 8
#define NT 800
#define NC 8
#define NF 513
#define NFT 9      // ceil(513/64) f-tiles of 64 lanes
#define NTC 20     // t chunks (blocks along t)
#define TCHUNK 40  // t per block
#define TS 4       // t per staged tile
#define NSTG (TCHUNK / TS)
#define NE 146     // 72 (psd_s tri) + 72 (psd_n tri) + S_s + S_n
#define NPAIR 36
#define STRIDE_BUF (72 * 64)   // floats per stage buffer: 64 x-rows + 8 mask-rows

// Compact layout: comp[((b*NFT+ft)*NE + entry)*64 + fl]
// entry 2p/2p+1    : psd_s pair p (c<=e), re/im, p = c*8 - c(c+1)/2 + e
// entry 72+2p/...+1: psd_n pair p
// entry 144/145    : S_s / S_n (accumulated over t-chunk blocks)

// Diagonal-grouped pair split: wave w owns 9 of the 36 (c<=e) pairs.
constexpr int PCt[4][9] = {
    {0, 1, 2, 3, 4, 5, 6, 7, 0},
    {0, 1, 2, 3, 4, 5, 6, 0, 1},
    {0, 1, 2, 3, 4, 5, 0, 1, 2},
    {0, 1, 2, 3, 4, 0, 1, 2, 3}};
constexpr int PEt[4][9] = {
    {0, 1, 2, 3, 4, 5, 6, 7, 7},
    {1, 2, 3, 4, 5, 6, 7, 6, 7},
    {2, 3, 4, 5, 6, 7, 5, 6, 7},
    {3, 4, 5, 6, 7, 4, 5, 6, 7}};

// ---------------------------------------------------------------------------
// Mask reduce over c + transpose -> mred[b][t][f], float4 loads along t.
__global__ __launch_bounds__(256)
void k_maskred(const float* __restrict__ ms, const float* __restrict__ mn,
               float* __restrict__ mrs, float* __restrict__ mrn) {
  __shared__ float ts[64][65];   // 65 pad: both phases <=2-way bank aliasing (free)
  __shared__ float tn[64][65];
  const int ft = blockIdx.x, tt = blockIdx.y, b = blockIdx.z;
  const int f0 = ft * 64, t0 = tt * 64;
  const int tq = threadIdx.x & 15;   // t-quad: 16 quads = 64 t
  const int fy = threadIdx.x >> 4;   // 0..15
  const int t = t0 + tq * 4;
  const bool tvalid = (t < NT);      // NT%4==0 so t<NT implies whole quad valid

#pragma unroll
  for (int p = 0; p < 4; p++) {
    const int fl = p * 16 + fy;
    const int f = f0 + fl;
    float4 as = make_float4(0.f, 0.f, 0.f, 0.f);
    float4 an = make_float4(0.f, 0.f, 0.f, 0.f);
    if (f < NF && tvalid) {
      const float* mbs = ms + (((size_t)b * NF + f) * NC) * NT + t;
      const float* mbn = mn + (((size_t)b * NF + f) * NC) * NT + t;
#pragma unroll
      for (int c = 0; c < NC; c++) {
        const float4 a = *(const float4*)(mbs + c * NT);
        as.x += fmaxf(a.x, 1e-6f); as.y += fmaxf(a.y, 1e-6f);
        as.z += fmaxf(a.z, 1e-6f); as.w += fmaxf(a.w, 1e-6f);
        const float4 q = *(const float4*)(mbn + c * NT);
        an.x += fmaxf(q.x, 1e-6f); an.y += fmaxf(q.y, 1e-6f);
        an.z += fmaxf(q.z, 1e-6f); an.w += fmaxf(q.w, 1e-6f);
      }
    }
    ts[fl][tq * 4 + 0] = as.x * 0.125f; ts[fl][tq * 4 + 1] = as.y * 0.125f;
    ts[fl][tq * 4 + 2] = as.z * 0.125f; ts[fl][tq * 4 + 3] = as.w * 0.125f;
    tn[fl][tq * 4 + 0] = an.x * 0.125f; tn[fl][tq * 4 + 1] = an.y * 0.125f;
    tn[fl][tq * 4 + 2] = an.z * 0.125f; tn[fl][tq * 4 + 3] = an.w * 0.125f;
  }
  __syncthreads();
  const int tx = threadIdx.x & 63, wy = threadIdx.x >> 6;
  for (int tl = wy; tl < 64; tl += 4) {
    const int tg = t0 + tl, f = f0 + tx;
    if (tg < NT && f < NF) {
      mrs[((size_t)b * NT + tg) * NF + f] = ts[tx][tl];
      mrn[((size_t)b * NT + tg) * NF + f] = tn[tx][tl];
    }
  }
}

// ---------------------------------------------------------------------------
// Stage TS t-steps of x (re,im; 8 c) + both masks into LDS via async
// global_load_lds (width 4: 64 lanes x 4B = one 256B row per instruction).
// Row layout: row = t*16 + c*2 + ri (rows 0..63), masks at 64 + t*2 + {s,n}.
__device__ __forceinline__ void stage_tile(const float* __restrict__ drb,
                                           const float* __restrict__ dib,
                                           const float* __restrict__ mrsb,
                                           const float* __restrict__ mrnb,
                                           float* buf, int tbase, int w, int fglob) {
#pragma unroll
  for (int r = 0; r < 18; ++r) {
    const int row = r * 4 + w;          // wave-uniform
    const float* src;
    if (r < 16) {                        // x rows (compile-time branch)
      const int t = row >> 4, c = (row >> 1) & 7;
      const float* base = (row & 1) ? dib : drb;
      src = base + ((size_t)(tbase + t) * NC + c) * NF + fglob;
    } else {                             // mask rows
      const int t = (row - 64) >> 1;
      const float* base = (row & 1) ? mrnb : mrsb;
      src = base + (size_t)(tbase + t) * NF + fglob;
    }
    __builtin_amdgcn_global_load_lds(
        (const __attribute__((address_space(1))) void*)src,
        (__attribute__((address_space(3))) void*)(buf + row * 64),
        4, 0, 0);
  }
}

template <int W>
__device__ __forceinline__ void psd_compute_tile(const float* __restrict__ buf,
                                                 int fl,
                                                 float sr[9], float si[9],
                                                 float nr[9], float ni[9],
                                                 float& Ss, float& Sn) {
#pragma unroll
  for (int t = 0; t < TS; ++t) {
    float xr[8], xi[8];
#pragma unroll
    for (int c = 0; c < 8; ++c) {
      xr[c] = buf[(t * 16 + c * 2 + 0) * 64 + fl];
      xi[c] = buf[(t * 16 + c * 2 + 1) * 64 + fl];
    }
    const float ms = buf[(64 + t * 2 + 0) * 64 + fl];
    const float mn = buf[(64 + t * 2 + 1) * 64 + fl];
    if (W == 0) { Ss += ms; Sn += mn; }
#pragma unroll
    for (int k = 0; k < 9; ++k) {
      const int c = PCt[W][k], e = PEt[W][k];   // folds after unroll
      const float pr = xr[c] * xr[e] + xi[c] * xi[e];
      sr[k] += ms * pr; nr[k] += mn * pr;
      if (c != e) {
        const float pi = xi[c] * xr[e] - xr[c] * xi[e];
        si[k] += ms * pi; ni[k] += mn * pi;
      }
    }
  }
}

template <int W>
__device__ __forceinline__ void psd_sweep(float* __restrict__ out,
                                          const float sr[9], const float si[9],
                                          const float nr[9], const float ni[9]) {
#pragma unroll
  for (int k = 0; k < 9; ++k) {
    const int c = PCt[W][k], e = PEt[W][k];
    const int p = c * 8 - (c * (c + 1)) / 2 + e;
    unsafeAtomicAdd(&out[(2 * p) * 64], sr[k]);
    unsafeAtomicAdd(&out[(72 + 2 * p) * 64], nr[k]);
    if (c != e) {
      unsafeAtomicAdd(&out[(2 * p + 1) * 64], si[k]);
      unsafeAtomicAdd(&out[(72 + 2 * p + 1) * 64], ni[k]);
    }
  }
}

// 4 waves per block share one (b,ft,tc) via LDS-staged x (double-buffered,
// async global_load_lds); waves own DISJOINT pair subsets (9 each, 36 acc
// regs/thread) so no cross-wave reduction is needed.
// __launch_bounds__(256,2): (256,4) hard-caps at 64 VGPR -> spill (R2: 1 GB,
// R4: 700 MB scratch traffic). At (256,2) this body fits (<116 regs, R3) and
// occupancy is LDS-limited: 36.9 KB -> 4 blocks/CU = 16 waves/CU.
__global__ __launch_bounds__(256, 2)
void k_psd(const float* __restrict__ dr, const float* __restrict__ di,
           const float* __restrict__ mrs, const float* __restrict__ mrn,
           float* __restrict__ comp) {
  __shared__ float lds[2 * STRIDE_BUF];   // 36,864 B
  const int tid = threadIdx.x;
  const int fl = tid & 63;
  const int w  = tid >> 6;
  const int ft = blockIdx.x, b = blockIdx.y, tc = blockIdx.z;
  const int fglob = min(ft * 64 + fl, NF - 1);
  const int t0 = tc * TCHUNK;

  const float* drb  = dr  + (size_t)b * NT * NC * NF;
  const float* dib  = di  + (size_t)b * NT * NC * NF;
  const float* mrsb = mrs + (size_t)b * NT * NF;
  const float* mrnb = mrn + (size_t)b * NT * NF;

  float sr[9], si[9], nr[9], ni[9];
#pragma unroll
  for (int k = 0; k < 9; ++k) { sr[k] = 0.f; si[k] = 0.f; nr[k] = 0.f; ni[k] = 0.f; }
  float Ss = 0.f, Sn = 0.f;

  stage_tile(drb, dib, mrsb, mrnb, &lds[0], t0, w, fglob);
  asm volatile("s_waitcnt vmcnt(0)" ::: "memory");
  __syncthreads();

  int cur = 0;
  for (int s = 0; s < NSTG; ++s) {
    if (s + 1 < NSTG)
      stage_tile(drb, dib, mrsb, mrnb, &lds[(cur ^ 1) * STRIDE_BUF],
                 t0 + (s + 1) * TS, w, fglob);
    const float* buf = &lds[cur * STRIDE_BUF];
    switch (w) {   // wave-uniform; no barriers inside arms
      case 0: psd_compute_tile<0>(buf, fl, sr, si, nr, ni, Ss, Sn); break;
      case 1: psd_compute_tile<1>(buf, fl, sr, si, nr, ni, Ss, Sn); break;
      case 2: psd_compute_tile<2>(buf, fl, sr, si, nr, ni, Ss, Sn); break;
      default: psd_compute_tile<3>(buf, fl, sr, si, nr, ni, Ss, Sn); break;
    }
    if (s + 1 < NSTG) {
      asm volatile("s_waitcnt vmcnt(0)" ::: "memory");   // next tile landed
      __syncthreads();
      cur ^= 1;
    }
  }

  // per-wave coalesced atomic sweep of its own 9 pairs (disjoint across waves)
  float* out = comp + ((size_t)(b * NFT + ft) * NE) * 64 + fl;
  switch (w) {
    case 0: psd_sweep<0>(out, sr, si, nr, ni); break;
    case 1: psd_sweep<1>(out, sr, si, nr, ni); break;
    case 2: psd_sweep<2>(out, sr, si, nr, ni); break;
    default: psd_sweep<3>(out, sr, si, nr, ni); break;
  }
  if (w == 0) {
    unsafeAtomicAdd(&out[144 * 64], Ss);
    unsafeAtomicAdd(&out[145 * 64], Sn);
  }
}

// ---------------------------------------------------------------------------
__global__ __launch_bounds__(320)
void k_attention(const float* __restrict__ comp,
                 const float* __restrict__ mlp_w, const float* __restrict__ mlp_b,
                 const float* __restrict__ gvec_w, const float* __restrict__ gvec_b,
                 float* __restrict__ e_buf) {
  __shared__ float feat[NF];
  __shared__ float wred[5];
  const int b = blockIdx.x >> 3, c = blockIdx.x & 7;
  const int tid = threadIdx.x;

  for (int f = tid; f < NF; f += 320) {
    const int ft = f >> 6, fl = f & 63;
    const float* base = comp + (((size_t)b * NFT + ft) * NE) * 64 + fl;
    float rs = 0.f, is = 0.f;
#pragma unroll
    for (int e = 0; e < NC; ++e) {
      if (e == c) continue;
      const int lo = (e < c) ? e : c, hi = (e < c) ? c : e;
      const int p = lo * 8 - (lo * (lo + 1)) / 2 + hi;
      rs += base[(2 * p) * 64];
      const float im = base[(2 * p + 1) * 64];
      is += (e > c) ? im : -im;   // row c: e<c needs conj
    }
    const float S = base[144 * 64];
    feat[f] = sqrtf(rs * rs + is * is) / (7.f * (S + 1e-15f));
  }
  __syncthreads();

  const int a = tid;  // blockDim == 320 == A
  float acc = mlp_b[a];
  for (int f = 0; f < NF; ++f) acc = fmaf(feat[f], mlp_w[f * 320 + a], acc);
  float contrib = tanhf(acc) * gvec_w[a];
#pragma unroll
  for (int off = 32; off > 0; off >>= 1) contrib += __shfl_down(contrib, off);
  if ((tid & 63) == 0) wred[tid >> 6] = contrib;
  __syncthreads();
  if (tid == 0) {
    float s = gvec_b[0];
#pragma unroll
    for (int w = 0; w < 5; ++w) s += wred[w];
    e_buf[blockIdx.x] = s;
  }
}

// ---------------------------------------------------------------------------
// Thread per (b,f,c): duplicated 8x8 complex Cholesky of psd_n per 8-lane
// group, one RHS column solve per thread, softmax(u) in-register,
// trace + u-weighted combine via shfl_xor butterflies over the 8-lane group.
__global__ __launch_bounds__(64)
void k_solve(const float* __restrict__ comp, const float* __restrict__ e_buf,
             float* __restrict__ wsvec) {
  const int lane = threadIdx.x;
  const int c = lane & 7, fsub = lane >> 3;
  const int b = blockIdx.y;
  const int f = blockIdx.x * 8 + fsub;
  if (f >= NF) return;
  const int ft = f >> 6, fl = f & 63;
  const float* base = comp + (((size_t)b * NFT + ft) * NE) * 64 + fl;

  float Ar[8][8], Ai[8][8];
#pragma unroll
  for (int j = 0; j < 8; j++) {
#pragma unroll
    for (int i = j; i < 8; i++) {
      const int p = j * 8 - (j * (j + 1)) / 2 + i;
      Ar[i][j] = base[(72 + 2 * p) * 64];
      Ai[i][j] = (i == j) ? 0.f : -base[(72 + 2 * p + 1) * 64];
    }
  }
#pragma unroll
  for (int i = 0; i < 8; i++) Ar[i][i] += 1e-15f;

  float dinv[8];
#pragma unroll
  for (int k = 0; k < 8; k++) {
    const float d = sqrtf(fmaxf(Ar[k][k], 1e-30f));
    const float id = 1.f / d;
    dinv[k] = id;
#pragma unroll
    for (int i = k + 1; i < 8; i++) { Ar[i][k] *= id; Ai[i][k] *= id; }
#pragma unroll
    for (int j = k + 1; j < 8; j++) {
#pragma unroll
      for (int i = j; i < 8; i++) {
        Ar[i][j] -= Ar[i][k] * Ar[j][k] + Ai[i][k] * Ai[j][k];
        Ai[i][j] -= Ai[i][k] * Ar[j][k] - Ar[i][k] * Ai[j][k];
      }
    }
  }

  // column c of psd_s: s[e] = psd_s[e][c]
  float syr[8], syi[8];
#pragma unroll
  for (int e = 0; e < 8; e++) {
    const int lo = (e < c) ? e : c, hi = (e < c) ? c : e;
    const int p = lo * 8 - (lo * (lo + 1)) / 2 + hi;
    syr[e] = base[(2 * p) * 64];
    const float im = base[(2 * p + 1) * 64];
    syi[e] = (e <= c) ? im : -im;
  }
  float yr[8], yi[8];
#pragma unroll
  for (int i = 0; i < 8; i++) {
    float ar = syr[i], ai = syi[i];
#pragma unroll
    for (int m = 0; m < 8; m++) {
      if (m < i) {
        ar -= Ar[i][m] * yr[m] - Ai[i][m] * yi[m];
        ai -= Ar[i][m] * yi[m] + Ai[i][m] * yr[m];
      }
    }
    yr[i] = ar * dinv[i]; yi[i] = ai * dinv[i];
  }
  float zr[8], zi[8];
#pragma unroll
  for (int i = 7; i >= 0; i--) {
    float ar = yr[i], ai = yi[i];
#pragma unroll
    for (int m = 0; m < 8; m++) {
      if (m > i) {
        ar -= Ar[m][i] * zr[m] + Ai[m][i] * zi[m];
        ai -= Ar[m][i] * zi[m] - Ai[m][i] * zr[m];
      }
    }
    zr[i] = ar * dinv[i]; zi[i] = ai * dinv[i];
  }

  // softmax(2*e) -> u[c]
  float ev[8], mx = -1e30f;
#pragma unroll
  for (int j = 0; j < 8; j++) { ev[j] = 2.f * e_buf[b * 8 + j]; mx = fmaxf(mx, ev[j]); }
  float ssum = 0.f;
#pragma unroll
  for (int j = 0; j < 8; j++) ssum += expf(ev[j] - mx);
  const float uc = expf(ev[c] - mx) / ssum;

  float trr = zr[c], tri = zi[c];
  float wr[8], wi[8];
#pragma unroll
  for (int e = 0; e < 8; e++) { wr[e] = zr[e] * uc; wi[e] = zi[e] * uc; }
#pragma unroll
  for (int m = 1; m <= 4; m <<= 1) {
    trr += __shfl_xor(trr, m); tri += __shfl_xor(tri, m);
#pragma unroll
    for (int e = 0; e < 8; e++) {
      wr[e] += __shfl_xor(wr[e], m);
      wi[e] += __shfl_xor(wi[e], m);
    }
  }

  const float denr = trr + 1e-15f, deni = tri;
  const float inv = 1.f / (denr * denr + deni * deni);
  float2* wv = (float2*)wsvec + ((size_t)b * NF + f) * 8;
  wv[c] = make_float2((wr[c] * denr + wi[c] * deni) * inv,
                      (wi[c] * denr - wr[c] * deni) * inv);
}

// ---------------------------------------------------------------------------
__global__ __launch_bounds__(64)
void k_apply(const float* __restrict__ dr, const float* __restrict__ di,
             const float* __restrict__ wsvec, float* __restrict__ out) {
  const int ft = blockIdx.x, b = blockIdx.y, tt = blockIdx.z;
  const int f = ft * 64 + threadIdx.x;
  if (f >= NF) return;
  float wr[8], wi[8];
  const float2* wv = (const float2*)wsvec + ((size_t)b * NF + f) * 8;
#pragma unroll
  for (int c = 0; c < 8; c++) { float2 w = wv[c]; wr[c] = w.x; wi[c] = w.y; }
  const float* drb = dr + (size_t)b * NT * NC * NF + f;
  const float* dib = di + (size_t)b * NT * NC * NF + f;
  float2* ob = (float2*)out + (size_t)b * NT * NF + f;
  const int t1 = tt * 8 + 8;
  for (int t = tt * 8; t < t1; ++t) {
    float re = 0.f, im = 0.f;
#pragma unroll
    for (int c = 0; c < 8; c++) {
      const float xr = drb[(t * NC + c) * NF];
      const float xi = dib[(t * NC + c) * NF];
      re += wr[c] * xr + wi[c] * xi;   // conj(ws) * x
      im += wr[c] * xi - wi[c] * xr;
    }
    ob[(size_t)t * NF] = make_float2(re, im);
  }
}

extern "C" void kernel_launch(void* const* d_in, const int* in_sizes, int n_in,
                              void* d_out, int out_size, void* d_ws, size_t ws_size,
                              hipStream_t stream) {
  const float* dr     = (const float*)d_in[0];
  const float* di     = (const float*)d_in[1];
  const float* msk_s  = (const float*)d_in[2];
  const float* msk_n  = (const float*)d_in[3];
  const float* mlp_w  = (const float*)d_in[4];
  const float* mlp_b  = (const float*)d_in[5];
  const float* gvec_w = (const float*)d_in[6];
  const float* gvec_b = (const float*)d_in[7];

  float* mrs   = (float*)d_ws;                                   // 3,283,200 floats
  float* mrn   = mrs + (size_t)NB * NT * NF;                     // 3,283,200
  float* comp  = mrn + (size_t)NB * NT * NF;                     // 672,768
  float* e_buf = comp + (size_t)NB * NFT * NE * 64;              // 64
  float* wsvec = e_buf + 64;                                     // 65,664
  float* out   = (float*)d_out;

  hipMemsetAsync(comp, 0, (size_t)NB * NFT * NE * 64 * sizeof(float), stream);
  k_maskred<<<dim3(NFT, 13, NB), 256, 0, stream>>>(msk_s, msk_n, mrs, mrn);
  k_psd<<<dim3(NFT, NB, NTC), 256, 0, stream>>>(dr, di, mrs, mrn, comp);
  k_attention<<<64, 320, 0, stream>>>(comp, mlp_w, mlp_b, gvec_w, gvec_b, e_buf);
  k_solve<<<dim3(65, NB), 64, 0, stream>>>(comp, e_buf, wsvec);
  k_apply<<<dim3(NFT, NB, 100), 64, 0, stream>>>(dr, di, wsvec, out);
}